// Round 2
// baseline (1037.609 us; speedup 1.0000x reference)
//
#include <hip/hip_runtime.h>
#include <math.h>

#define BATCH 16
#define CDIM 256
#define NCLS 80
#define N3 16384
#define N4 4096
#define N5 1024
#define NTOK 21504
#define KQ 300
#define KSEL 512
#define CANDMAX 1024

typedef __attribute__((ext_vector_type(8))) short short8;
typedef __attribute__((ext_vector_type(4))) float floatx4;
typedef __attribute__((ext_vector_type(16))) float floatx16;
typedef unsigned short ushort_t;

__device__ __forceinline__ float sigmoidf_(float x) {
    return 1.0f / (1.0f + __expf(-x));
}

__device__ __forceinline__ ushort_t f2bf(float f) {   // RNE f32->bf16
    unsigned int x = __float_as_uint(f);
    unsigned int r = (x + 0x7FFFu + ((x >> 16) & 1u)) >> 16;
    return (ushort_t)r;
}

__device__ __forceinline__ float bf2f(ushort_t u) {
    return __uint_as_float((unsigned int)u << 16);
}

__device__ __forceinline__ void locate_level(
    int n, int bb,
    const float* __restrict__ s3, const float* __restrict__ s4, const float* __restrict__ s5,
    const float*& src, int& nloc, int& lsz)
{
    if (n < N3)           { src = s3 + (size_t)bb * CDIM * N3; nloc = n;           lsz = N3; }
    else if (n < N3 + N4) { src = s4 + (size_t)bb * CDIM * N4; nloc = n - N3;      lsz = N4; }
    else                  { src = s5 + (size_t)bb * CDIM * N5; nloc = n - N3 - N4; lsz = N5; }
}

// -------- Kernel 0: pack weights into 32x32x16-MFMA fragment order --------
// 19 chunks of 32 cols (0..2: w_score padded to 96; 3..10: w1; 11..18: w2).
// Per chunk: 16 K-frags; frag f, lane l holds W^T[col=cb+(l&31)][k=16f+(l>>5)*8 .. +8)
// as 8 consecutive bf16. A wave's B-frag load = one coalesced 1KB global_load_dwordx4.
__global__ __launch_bounds__(256) void prep_weights(
    const float* __restrict__ w1, const float* __restrict__ w2,
    const float* __restrict__ w_score,
    ushort_t* __restrict__ wPk)
{
    const int c = blockIdx.x;          // 0..18
    for (int i = threadIdx.x; i < 8192; i += 256) {
        const int f = i >> 9;          // 0..15
        const int e = i & 511;
        const int ln = e >> 3;         // 0..63 (lane)
        const int j = e & 7;
        const int col = ln & 31;
        const int k = 16 * f + (ln >> 5) * 8 + j;
        float v;
        if (c < 3) {
            const int cc = 32 * c + col;
            v = (cc < NCLS) ? w_score[k * NCLS + cc] : 0.f;
        } else if (c < 11) {
            v = w1[k * 256 + (32 * (c - 3) + col)];
        } else {
            v = w2[k * 256 + (32 * (c - 11) + col)];
        }
        wPk[(size_t)c * 8192 + i] = f2bf(v);
    }
}

// -------- Kernel 1: fused encoder head, 32x32x16 bf16 MFMA, B direct from L2 --------
// grid: BATCH*336 blocks (64 tokens), 256 threads = 4 waves.
// wave w: token-tile tw=w&1 (32 tokens), chunk parity cw=w>>1.
// No LDS for B: fragments load coalesced from wPk (L2/L1-resident).
// ldsA: memB[k=256][tok=68pad] bf16, then reused as h1/h2 [64][256] XOR-swizzled.
__global__ __launch_bounds__(256) void enc_mfma_kernel(
    const float* __restrict__ s3, const float* __restrict__ s4, const float* __restrict__ s5,
    const ushort_t* __restrict__ wPk,
    const float* __restrict__ b_score, const float* __restrict__ b1,
    const float* __restrict__ b2,
    const float* __restrict__ w3, const float* __restrict__ b3,
    float* __restrict__ out_logits, float* __restrict__ out_sboxes,
    float* __restrict__ ws_scores)
{
    __shared__ __align__(16) ushort_t ldsA[256 * 68];   // 34816 B; h1/h2 reuse [64][256]
    __shared__ __align__(16) float w3_s[256 * 4];       // 4096 B
    __shared__ float smax_s[2][64];                     // 512 B

    const int t = threadIdx.x;
    const int lane = t & 63;
    const int w = t >> 6;
    const int tw = w & 1;                // token tile: rows [32tw, 32tw+32)
    const int cw = w >> 1;               // chunk parity
    const int ln = lane & 31;
    const int half = lane >> 5;

    const int bb = blockIdx.x / 336;
    const int tile = blockIdx.x % 336;
    const int T0 = tile * 64;

    const float* src; int nloc, lsz;
    locate_level(T0, bb, s3, s4, s5, src, nloc, lsz);

    // ---- stage memory tile [k][tok] f32 -> bf16 LDS; preload w3 ----
    {
        const int tokq = t & 15;
        const int kr = t >> 4;
        #pragma unroll
        for (int p = 0; p < 16; ++p) {
            const int k = p * 16 + kr;
            const float4 v = *(const float4*)(src + (size_t)k * lsz + nloc + 4 * tokq);
            const unsigned int lo = (unsigned int)f2bf(v.x) | ((unsigned int)f2bf(v.y) << 16);
            const unsigned int hi = (unsigned int)f2bf(v.z) | ((unsigned int)f2bf(v.w) << 16);
            *(uint2*)&ldsA[k * 68 + 4 * tokq] = make_uint2(lo, hi);
        }
        *(float4*)&w3_s[t * 4] = *(const float4*)(w3 + t * 4);
    }
    __syncthreads();                                    // B1: memB + w3 ready

    // ---- A1 fragments: memory[tok=32tw+ln][k], k = 16f + 8*half + j ----
    short8 af[16];
    #pragma unroll
    for (int f = 0; f < 16; ++f) {
        short8 a;
        #pragma unroll
        for (int j = 0; j < 8; ++j)
            a[j] = (short)ldsA[(16 * f + 8 * half + j) * 68 + 32 * tw + ln];
        af[f] = a;
    }
    __syncthreads();                                    // B2: all A1 reads done (h1 may overwrite)

    const int gtok0 = bb * NTOK + T0 + 32 * tw;

    // ---- chunks 0..10 (score + w1), parity-split ----
    float smaxr[16];
    #pragma unroll
    for (int r = 0; r < 16; ++r) smaxr[r] = -1e30f;

    for (int c = cw; c < 11; c += 2) {
        const ushort_t* bp = wPk + (size_t)c * 8192;
        floatx16 acc = {0.f,0.f,0.f,0.f,0.f,0.f,0.f,0.f,0.f,0.f,0.f,0.f,0.f,0.f,0.f,0.f};
        #pragma unroll
        for (int fh = 0; fh < 2; ++fh) {
            short8 bf[8];
            #pragma unroll
            for (int f2 = 0; f2 < 8; ++f2)
                bf[f2] = *(const short8*)&bp[(8 * fh + f2) * 512 + lane * 8];
            #pragma unroll
            for (int f2 = 0; f2 < 8; ++f2)
                acc = __builtin_amdgcn_mfma_f32_32x32x16_bf16(af[8 * fh + f2], bf[f2], acc, 0, 0, 0);
        }
        if (c < 3) {
            const int col = 32 * c + ln;
            const bool valid = col < NCLS;
            const float bias = valid ? b_score[col] : 0.f;
            #pragma unroll
            for (int r = 0; r < 16; ++r) {
                const int row = (r & 3) + 8 * (r >> 2) + 4 * half;
                const float v = acc[r] + bias;
                if (valid) {
                    out_logits[(size_t)(gtok0 + row) * NCLS + col] = v;
                    smaxr[r] = fmaxf(smaxr[r], v);
                }
            }
        } else {
            const int col = 32 * (c - 3) + ln;
            const float bias = b1[col];
            #pragma unroll
            for (int r = 0; r < 16; ++r) {
                const int row = (r & 3) + 8 * (r >> 2) + 4 * half;
                const int tok = 32 * tw + row;
                const float v = fmaxf(acc[r] + bias, 0.f);
                ldsA[tok * 256 + ((((col >> 3) ^ (row & 7)) << 3) | (col & 7))] = f2bf(v);
            }
        }
    }

    // per-row score max: reduce over the 32 col-lanes of each half, stash in LDS
    #pragma unroll
    for (int r = 0; r < 16; ++r) {
        float m = smaxr[r];
        m = fmaxf(m, __shfl_xor(m, 1));
        m = fmaxf(m, __shfl_xor(m, 2));
        m = fmaxf(m, __shfl_xor(m, 4));
        m = fmaxf(m, __shfl_xor(m, 8));
        m = fmaxf(m, __shfl_xor(m, 16));
        if (ln == 0) {
            const int row = (r & 3) + 8 * (r >> 2) + 4 * half;
            smax_s[cw][32 * tw + row] = m;
        }
    }
    __syncthreads();                                    // B3: h1 + smax complete

    if (t < 64) {
        const float m = fmaxf(smax_s[0][t], smax_s[1][t]);
        ws_scores[bb * NTOK + T0 + t] = sigmoidf_(m);
    }

    // ---- A2 fragments from h1 (b128, swizzled) ----
    {
        const int tok = 32 * tw + ln;
        #pragma unroll
        for (int f = 0; f < 16; ++f) {
            const int chnk = 2 * f + half;
            af[f] = *(const short8*)&ldsA[tok * 256 + ((chnk ^ (tok & 7)) << 3)];
        }
    }
    __syncthreads();                                    // B4: all A2 reads done (h2 may overwrite)

    // ---- chunks 11..18 (w2) -> h2 (same buffer, same swizzle) ----
    for (int c = 11 + cw; c < 19; c += 2) {
        const ushort_t* bp = wPk + (size_t)c * 8192;
        floatx16 acc = {0.f,0.f,0.f,0.f,0.f,0.f,0.f,0.f,0.f,0.f,0.f,0.f,0.f,0.f,0.f,0.f};
        #pragma unroll
        for (int fh = 0; fh < 2; ++fh) {
            short8 bf[8];
            #pragma unroll
            for (int f2 = 0; f2 < 8; ++f2)
                bf[f2] = *(const short8*)&bp[(8 * fh + f2) * 512 + lane * 8];
            #pragma unroll
            for (int f2 = 0; f2 < 8; ++f2)
                acc = __builtin_amdgcn_mfma_f32_32x32x16_bf16(af[8 * fh + f2], bf[f2], acc, 0, 0, 0);
        }
        const int col = 32 * (c - 11) + ln;
        const float bias = b2[col];
        #pragma unroll
        for (int r = 0; r < 16; ++r) {
            const int row = (r & 3) + 8 * (r >> 2) + 4 * half;
            const int tok = 32 * tw + row;
            const float v = fmaxf(acc[r] + bias, 0.f);
            ldsA[tok * 256 + ((((col >> 3) ^ (row & 7)) << 3) | (col & 7))] = f2bf(v);
        }
    }
    __syncthreads();                                    // B5: h2 complete

    // ---- boxes: h2 @ w3 (+b3), sigmoid ----
    {
        const int tok = t >> 2;
        const int j = t & 3;
        float acc = b3[j];
        #pragma unroll
        for (int ch = 0; ch < 32; ++ch) {
            const short8 v = *(const short8*)&ldsA[tok * 256 + ((ch ^ (tok & 7)) << 3)];
            #pragma unroll
            for (int jj = 0; jj < 8; ++jj)
                acc = fmaf(bf2f((ushort_t)v[jj]), w3_s[(ch * 8 + jj) * 4 + j], acc);
        }
        out_sboxes[(size_t)(bb * NTOK + T0 + tok) * 4 + j] = sigmoidf_(acc);
    }
}

// -------- Kernel 2: fp32 radix pre-select of top-KSEL candidates per batch --------
// One-ballot aggregation: the dominant-bin lanes fold into a single atomic
// (kills the pass-0 same-bin storm), stragglers add individually.
__global__ __launch_bounds__(256) void select_kernel(
    const float* __restrict__ scores,
    int* __restrict__ cand_idx, unsigned int* __restrict__ cand_cnt)
{
    const int bb = blockIdx.x;
    const int t = threadIdx.x;
    const int lane = t & 63;
    const float* s = scores + bb * NTOK;

    __shared__ unsigned int hist[256];
    __shared__ unsigned int prefix_s, rem_s, cnt_s;

    unsigned int prefix = 0, mask = 0;
    int remaining = KSEL;
    for (int pass = 0; pass < 4; pass++) {
        const int shift = 24 - 8 * pass;
        hist[t] = 0;
        __syncthreads();
        for (int n = t; n < NTOK; n += 256) {
            const unsigned int key = __float_as_uint(s[n]);
            const bool pred = ((key & mask) == prefix);
            const unsigned int bin = pred ? ((key >> shift) & 255u) : 0xFFFFu;
            const unsigned long long alive = __ballot(pred);
            if (alive) {
                const int leader = __builtin_ctzll(alive);
                const unsigned int lbin = (unsigned int)__shfl((int)bin, leader);
                const unsigned long long match = __ballot(pred && bin == lbin);
                if (lane == leader)
                    atomicAdd(&hist[lbin], (unsigned int)__popcll(match));
                else if (pred && bin != lbin)
                    atomicAdd(&hist[bin], 1u);
            }
        }
        __syncthreads();
        if (t == 0) {
            int rem = remaining; unsigned int bsel = 0;
            for (int bin = 255; bin >= 0; bin--) {
                int c = (int)hist[bin];
                if (c >= rem) { bsel = (unsigned int)bin; break; }
                rem -= c;
            }
            prefix_s = prefix | (bsel << shift);
            rem_s = (unsigned int)rem;
        }
        __syncthreads();
        prefix = prefix_s; remaining = (int)rem_s;
        mask |= 0xFFu << shift;
        __syncthreads();
    }
    const unsigned int Tkey = prefix;

    if (t == 0) cnt_s = 0;
    __syncthreads();
    for (int n = t; n < NTOK; n += 256) {
        const unsigned int key = __float_as_uint(s[n]);
        const bool pred = (key >= Tkey);
        const unsigned long long m = __ballot(pred);
        if (m) {
            const int leader = __builtin_ctzll(m);
            unsigned int base = 0;
            if (lane == leader) base = atomicAdd(&cnt_s, (unsigned int)__popcll(m));
            base = (unsigned int)__shfl((int)base, leader);
            if (pred) {
                const unsigned int pos =
                    base + (unsigned int)__popcll(m & ((1ull << lane) - 1ull));
                if (pos < CANDMAX) cand_idx[bb * CANDMAX + pos] = n;
            }
        }
    }
    __syncthreads();
    if (t == 0) {
        unsigned int c = cnt_s; if (c > CANDMAX) c = CANDMAX;
        cand_cnt[bb] = c;
    }
}

// -------- Kernel 3: f64 exact rescore (one wave per candidate) --------
__global__ __launch_bounds__(256) void rescore_kernel(
    const float* __restrict__ s3, const float* __restrict__ s4, const float* __restrict__ s5,
    const float* __restrict__ w_score, const float* __restrict__ b_score,
    const int* __restrict__ cand_idx, const unsigned int* __restrict__ cand_cnt,
    double* __restrict__ cand_score)
{
    __shared__ float mrow[4][CDIM];
    const int t = threadIdx.x;
    const int w = t >> 6;
    const int lane = t & 63;
    const int bb = blockIdx.x / (CANDMAX / 4);
    const int c  = (blockIdx.x % (CANDMAX / 4)) * 4 + w;
    const unsigned int cnt = cand_cnt[bb];
    const bool active = (unsigned int)c < cnt;

    int n = 0;
    if (active) n = cand_idx[bb * CANDMAX + c];
    if (active) {
        const float* src; int nloc, lsz;
        locate_level(n, bb, s3, s4, s5, src, nloc, lsz);
        #pragma unroll
        for (int j = 0; j < 4; j++)
            mrow[w][4 * lane + j] = src[(size_t)(4 * lane + j) * lsz + nloc];
    }
    __syncthreads();

    if (active) {
        double acc0 = (double)b_score[lane];
        double acc1 = (lane < 16) ? (double)b_score[64 + lane] : -1.0e300;
        for (int k = 0; k < CDIM; k++) {
            const double m = (double)mrow[w][k];
            acc0 += m * (double)w_score[k * NCLS + lane];
            if (lane < 16) acc1 += m * (double)w_score[k * NCLS + 64 + lane];
        }
        double mx = fmax(acc0, acc1);
        mx = fmax(mx, __shfl_xor(mx, 1));
        mx = fmax(mx, __shfl_xor(mx, 2));
        mx = fmax(mx, __shfl_xor(mx, 4));
        mx = fmax(mx, __shfl_xor(mx, 8));
        mx = fmax(mx, __shfl_xor(mx, 16));
        mx = fmax(mx, __shfl_xor(mx, 32));
        if (lane == 0) cand_score[bb * CANDMAX + c] = mx;
    }
}

// -------- Kernel 4: exact sort of candidates, emit top-300 --------
__global__ __launch_bounds__(256) void fsort_kernel(
    const double* __restrict__ cand_score, const int* __restrict__ cand_idx,
    const unsigned int* __restrict__ cand_cnt,
    float* __restrict__ out_idx_f, float* __restrict__ out_scores,
    int* __restrict__ ws_idx)
{
    __shared__ double ss[CANDMAX];
    __shared__ int    ii[CANDMAX];
    const int bb = blockIdx.x;
    const int t = threadIdx.x;
    const unsigned int cnt = cand_cnt[bb];

    for (int i = t; i < CANDMAX; i += 256) {
        if ((unsigned int)i < cnt) {
            ss[i] = cand_score[bb * CANDMAX + i];
            ii[i] = cand_idx[bb * CANDMAX + i];
        } else {
            ss[i] = -1.0e300;
            ii[i] = 0x7FFFFFFF;
        }
    }
    __syncthreads();

    for (int ksz = 2; ksz <= CANDMAX; ksz <<= 1) {
        for (int j = ksz >> 1; j > 0; j >>= 1) {
            #pragma unroll
            for (int p = 0; p < CANDMAX / 256; p++) {
                const int i = p * 256 + t;
                const int ixj = i ^ j;
                if (ixj > i) {
                    double sa = ss[i], sb = ss[ixj];
                    int ia = ii[i], ib = ii[ixj];
                    const bool up = ((i & ksz) != 0);
                    const bool agtb = (sa > sb) || (sa == sb && ia < ib);
                    if (agtb == up) { ss[i] = sb; ss[ixj] = sa; ii[i] = ib; ii[ixj] = ia; }
                }
            }
            __syncthreads();
        }
    }

    for (int q = t; q < KQ; q += 256) {
        const double x = ss[q];
        const int idx = ii[q];
        out_scores[bb * KQ + q] = (float)(1.0 / (1.0 + exp(-x)));
        out_idx_f[bb * KQ + q] = (float)idx;
        ws_idx[bb * KQ + q] = idx;
    }
}

// -------- Kernel 5: gather top-k memory rows, project, gather ref_points --------
__global__ __launch_bounds__(256) void gather_proj_kernel(
    const float* __restrict__ s3, const float* __restrict__ s4, const float* __restrict__ s5,
    const float* __restrict__ w_proj, const float* __restrict__ b_proj,
    const int* __restrict__ ws_idx, const float* __restrict__ out_sboxes,
    float* __restrict__ out_tgt, float* __restrict__ out_ref)
{
    __shared__ float memQ[20][CDIM];
    __shared__ int qidx[20];
    const int t = threadIdx.x;
    const int bb = blockIdx.x / 15;
    const int tile = blockIdx.x % 15;
    const int q0 = tile * 20;

    if (t < 20) qidx[t] = ws_idx[bb * KQ + q0 + t];
    __syncthreads();

    #pragma unroll 4
    for (int q = 0; q < 20; q++) {
        const int n = qidx[q];
        const float* src; int nloc, lsz;
        locate_level(n, bb, s3, s4, s5, src, nloc, lsz);
        memQ[q][t] = src[(size_t)t * lsz + nloc];
    }
    __syncthreads();

    const int j = t;
    float acc[20];
    #pragma unroll
    for (int q = 0; q < 20; q++) acc[q] = b_proj[j];
    for (int k = 0; k < CDIM; k++) {
        const float w = w_proj[(size_t)k * CDIM + j];
        #pragma unroll
        for (int q = 0; q < 20; q++) acc[q] = fmaf(memQ[q][k], w, acc[q]);
    }
    #pragma unroll
    for (int q = 0; q < 20; q++)
        out_tgt[(size_t)(bb * KQ + q0 + q) * CDIM + j] = acc[q];

    if (t < 80) {
        const int q = t >> 2, c = t & 3;
        const int n = qidx[q];
        out_ref[(size_t)(bb * KQ + q0 + q) * 4 + c] =
            out_sboxes[(size_t)(bb * NTOK + n) * 4 + c];
    }
}

extern "C" void kernel_launch(void* const* d_in, const int* in_sizes, int n_in,
                              void* d_out, int out_size, void* d_ws, size_t ws_size,
                              hipStream_t stream) {
    const float* s3      = (const float*)d_in[0];
    const float* s4      = (const float*)d_in[1];
    const float* s5      = (const float*)d_in[2];
    const float* w_score = (const float*)d_in[3];
    const float* b_score = (const float*)d_in[4];
    const float* w1      = (const float*)d_in[5];
    const float* b1      = (const float*)d_in[6];
    const float* w2      = (const float*)d_in[7];
    const float* b2      = (const float*)d_in[8];
    const float* w3      = (const float*)d_in[9];
    const float* b3      = (const float*)d_in[10];
    const float* w_proj  = (const float*)d_in[11];
    const float* b_proj  = (const float*)d_in[12];

    float* out = (float*)d_out;
    float* out_tgt    = out;                 // 16*300*256
    float* out_ref    = out + 1228800;       // 16*300*4
    float* out_logits = out + 1248000;       // 16*21504*80
    float* out_sboxes = out + 28773120;      // 16*21504*4
    float* out_idx    = out + 30149376;      // 16*300 (as float)
    float* out_scores = out + 30154176;      // 16*300

    char* ws = (char*)d_ws;
    float*        ws_scores  = (float*)(ws + 0);            // 1,376,256
    double*       cand_score = (double*)(ws + 1376256);     //   131,072
    int*          cand_idx   = (int*)(ws + 1507328);        //    65,536
    unsigned int* cand_cnt   = (unsigned int*)(ws + 1572864); //      256
    int*          ws_idx     = (int*)(ws + 1573120);        //    19,456
    ushort_t*     wPk        = (ushort_t*)(ws + 1592576);   //   311,296 (19*16KB)

    prep_weights<<<19, 256, 0, stream>>>(w1, w2, w_score, wPk);

    enc_mfma_kernel<<<BATCH * 336, 256, 0, stream>>>(
        s3, s4, s5, wPk, b_score, b1, b2, w3, b3,
        out_logits, out_sboxes, ws_scores);

    select_kernel<<<BATCH, 256, 0, stream>>>(ws_scores, cand_idx, cand_cnt);

    rescore_kernel<<<BATCH * (CANDMAX / 4), 256, 0, stream>>>(
        s3, s4, s5, w_score, b_score, cand_idx, cand_cnt, cand_score);

    fsort_kernel<<<BATCH, 256, 0, stream>>>(
        cand_score, cand_idx, cand_cnt, out_idx, out_scores, ws_idx);

    gather_proj_kernel<<<BATCH * 15, 256, 0, stream>>>(
        s3, s4, s5, w_proj, b_proj, ws_idx, out_sboxes, out_tgt, out_ref);
}